// Round 5
// baseline (110.545 us; speedup 1.0000x reference)
//
#include <hip/hip_runtime.h>

#define BLOCK 256
#define LOG_2PI_F 1.8378770664093453f

// ws layout (float offsets):
//   0..7     : stats: [2] ld_sum0 [3] ld_sum1 [4] cnt0 [5] cnt1
//   16       : p_tab [2*D]   (= 0.5*exp(-2*lsd))
//   16+2D    : q_tab [2*D]   (= 2*p*mu)
//   16+4D    : b_tab [2*D]   (= -0.5*log2pi - lsd - p*mu^2)
//   16+6D    : tgtf  [N]     (= (float)(target[n]!=0))
//   PART0    : partials [2(z)][gyR][gx][2][1024]  (plane 0 = sumAll, 1 = sumC1)

// one block: build tgtf + counts + logdet sums
__global__ __launch_bounds__(1024) void k_prep(
    const int*   __restrict__ target,
    const float* __restrict__ logdet,
    float* __restrict__ tgtf,
    float* __restrict__ stats,
    int N)
{
    const int tid = threadIdx.x;
    float ldA = 0.f, ld1 = 0.f;
    int   c1  = 0;
    if ((N & 4095) == 0) {
        const int4*   t4 = reinterpret_cast<const int4*>(target);
        const float4* l4 = reinterpret_cast<const float4*>(logdet);
        float4*       g4 = reinterpret_cast<float4*>(tgtf);
        const int n4 = N >> 2;
        for (int i = tid; i < n4; i += 1024) {
            const int4   t = t4[i];
            const float4 v = l4[i];
            float4 w;
            w.x = t.x ? 1.f : 0.f;
            w.y = t.y ? 1.f : 0.f;
            w.z = t.z ? 1.f : 0.f;
            w.w = t.w ? 1.f : 0.f;
            g4[i] = w;
            ldA += v.x + v.y + v.z + v.w;
            ld1 += w.x * v.x + w.y * v.y + w.z * v.z + w.w * v.w;
            c1  += (t.x ? 1 : 0) + (t.y ? 1 : 0) + (t.z ? 1 : 0) + (t.w ? 1 : 0);
        }
    } else {
        for (int n = tid; n < N; n += 1024) {
            const int   t = target[n];
            const float v = logdet[n];
            const float w = t ? 1.f : 0.f;
            tgtf[n] = w;
            ldA += v; ld1 += w * v; c1 += t ? 1 : 0;
        }
    }
    __shared__ float sB[1024], sC[1024];
    __shared__ int   sI[1024];
    sB[tid] = ldA; sC[tid] = ld1; sI[tid] = c1;
    __syncthreads();
    for (int off = 512; off > 0; off >>= 1) {
        if (tid < off) {
            sB[tid] += sB[tid + off];
            sC[tid] += sC[tid + off];
            sI[tid] += sI[tid + off];
        }
        __syncthreads();
    }
    if (tid == 0) {
        stats[2] = sB[0] - sC[0];          // ld_sum0
        stats[3] = sC[0];                  // ld_sum1
        stats[4] = (float)(N - sI[0]);     // cnt0
        stats[5] = (float)sI[0];           // cnt1
    }
}

// streaming column partial sums: thread <-> one float4 column, loop over rows
__global__ __launch_bounds__(BLOCK, 4) void k_colsum(
    const float* __restrict__ mean,
    const float* __restrict__ log_sd,
    const float* __restrict__ tgtf,
    float* __restrict__ partials,
    int N, int D4, int rowsPerBlk, int gyR)
{
    const int c4 = blockIdx.x * BLOCK + threadIdx.x;   // float4 column
    const bool colOK = (c4 < D4);
    const int rowBase = blockIdx.y * rowsPerBlk;
    const int rEnd = (rowBase + rowsPerBlk <= N) ? rowsPerBlk : (N - rowBase);

    const float4* src4 =
        reinterpret_cast<const float4*>(blockIdx.z == 0 ? mean : log_sd);
    const float4* p = src4 + (size_t)rowBase * D4 + (colOK ? c4 : 0);
    const float*  wp = tgtf + rowBase;

    float4 sA = make_float4(0.f, 0.f, 0.f, 0.f);
    float4 s1 = make_float4(0.f, 0.f, 0.f, 0.f);

    int r = 0;
    for (; r + 16 <= rEnd; r += 16) {
        // 16 independent loads issued back-to-back + 16 uniform weight loads
        float4 d[16];
        float  w[16];
        #pragma unroll
        for (int k = 0; k < 16; ++k)
            d[k] = p[(size_t)(r + k) * D4];
        #pragma unroll
        for (int k = 0; k < 16; ++k)
            w[k] = wp[r + k];
        #pragma unroll
        for (int k = 0; k < 16; ++k) {
            sA.x += d[k].x; sA.y += d[k].y; sA.z += d[k].z; sA.w += d[k].w;
            s1.x = fmaf(d[k].x, w[k], s1.x);
            s1.y = fmaf(d[k].y, w[k], s1.y);
            s1.z = fmaf(d[k].z, w[k], s1.z);
            s1.w = fmaf(d[k].w, w[k], s1.w);
        }
    }
    for (; r < rEnd; ++r) {
        const float4 d = p[(size_t)r * D4];
        const float  w = wp[r];
        sA.x += d.x; sA.y += d.y; sA.z += d.z; sA.w += d.w;
        s1.x = fmaf(d.x, w, s1.x);
        s1.y = fmaf(d.y, w, s1.y);
        s1.z = fmaf(d.z, w, s1.z);
        s1.w = fmaf(d.w, w, s1.w);
    }

    if (colOK) {
        // partials tile: [2 planes][1024 floats], coalesced float4 stores
        float* pt = partials +
            (((size_t)blockIdx.z * gyR + blockIdx.y) * gridDim.x + blockIdx.x) * 2048;
        reinterpret_cast<float4*>(pt)[threadIdx.x]        = sA;   // sumAll
        reinterpret_cast<float4*>(pt + 1024)[threadIdx.x] = s1;   // sumC1
    }
}

// reduce partials over gyR, finalize class params, build logp tables
__global__ __launch_bounds__(BLOCK) void k_reduce_finalize(
    const float* __restrict__ partials,
    const float* __restrict__ stats,
    float* __restrict__ ws,
    float* __restrict__ out,
    int D, int gx, int gyR)
{
    const int idx = blockIdx.x * BLOCK + threadIdx.x;   // [0, 2*D)
    if (idx >= 2 * D) return;
    const int cls = idx / D;
    const int col = idx - cls * D;
    const int bx  = col >> 10;          // 1024 floats per column-block
    const int cc  = col & 1023;

    const size_t strideY = (size_t)gx * 2048;
    const float* pm = partials + (size_t)bx * 2048 + cc;   // z=0 (mean)
    const float* pl = pm + (size_t)gyR * strideY;          // z=1 (log_sd)

    float mA = 0.f, m1 = 0.f, lA = 0.f, l1 = 0.f;
    for (int by = 0; by < gyR; ++by) {
        const size_t o = (size_t)by * strideY;
        mA += pm[o]; m1 += pm[o + 1024];
        lA += pl[o]; l1 += pl[o + 1024];
    }
    const float cnt = stats[4 + cls];
    const float sm  = cls ? m1 : (mA - m1);
    const float sl  = cls ? l1 : (lA - l1);
    const float m = sm / cnt;
    const float l = sl / cnt;
    out[1 + idx]         = m;   // mus
    out[1 + 2 * D + idx] = l;   // lsds

    float* p_tab = ws + 16;
    float* q_tab = p_tab + 2 * D;
    float* b_tab = q_tab + 2 * D;
    const float p = 0.5f * expf(-2.f * l);
    p_tab[idx] = p;
    q_tab[idx] = 2.f * p * m;
    b_tab[idx] = -0.5f * LOG_2PI_F - l - p * m * m;
}

__global__ __launch_bounds__(BLOCK, 4) void k_logp(
    const float* __restrict__ z,
    const int*   __restrict__ target,
    const float* __restrict__ ws,
    float* __restrict__ logp_out,
    int N, int D)
{
    const int wave = threadIdx.x >> 6;
    const int lane = threadIdx.x & 63;
    const int n    = blockIdx.x * 4 + wave;
    const int D4   = D >> 2;
    if (n >= N) return;

    const int t = __builtin_amdgcn_readfirstlane(target[n]);
    const float4* z4 = reinterpret_cast<const float4*>(z) + (size_t)n * D4;
    const float4* p4 = reinterpret_cast<const float4*>(ws + 16) + (size_t)t * D4;
    const float4* q4 = p4 + 2 * D4;
    const float4* b4 = q4 + 2 * D4;

    float acc = 0.f;
    int i = lane;
    for (; i + 64 < D4; i += 128) {
        const float4 zz0 = z4[i];      const float4 zz1 = z4[i + 64];
        const float4 pp0 = p4[i];      const float4 pp1 = p4[i + 64];
        const float4 qq0 = q4[i];      const float4 qq1 = q4[i + 64];
        const float4 bb0 = b4[i];      const float4 bb1 = b4[i + 64];
        acc += bb0.x + zz0.x * (qq0.x - pp0.x * zz0.x);
        acc += bb0.y + zz0.y * (qq0.y - pp0.y * zz0.y);
        acc += bb0.z + zz0.z * (qq0.z - pp0.z * zz0.z);
        acc += bb0.w + zz0.w * (qq0.w - pp0.w * zz0.w);
        acc += bb1.x + zz1.x * (qq1.x - pp1.x * zz1.x);
        acc += bb1.y + zz1.y * (qq1.y - pp1.y * zz1.y);
        acc += bb1.z + zz1.z * (qq1.z - pp1.z * zz1.z);
        acc += bb1.w + zz1.w * (qq1.w - pp1.w * zz1.w);
    }
    for (; i < D4; i += 64) {
        const float4 zz = z4[i];
        const float4 pp = p4[i];
        const float4 qq = q4[i];
        const float4 bb = b4[i];
        acc += bb.x + zz.x * (qq.x - pp.x * zz.x);
        acc += bb.y + zz.y * (qq.y - pp.y * zz.y);
        acc += bb.z + zz.z * (qq.z - pp.z * zz.z);
        acc += bb.w + zz.w * (qq.w - pp.w * zz.w);
    }

    #pragma unroll
    for (int m = 32; m >= 1; m >>= 1) acc += __shfl_xor(acc, m);
    if (lane == 0) logp_out[n] = acc;
}

__global__ __launch_bounds__(1024) void k_finalize2(
    const float* __restrict__ logp,
    const int*   __restrict__ target,
    const float* __restrict__ stats,
    float* __restrict__ out,
    int N, int out_off)
{
    const int tid = threadIdx.x;
    float cA = 0.f, c1 = 0.f;
    if ((N & 4095) == 0) {
        const float4* lp4 = reinterpret_cast<const float4*>(logp);
        const int4*   t4  = reinterpret_cast<const int4*>(target);
        for (int i = tid; i < (N >> 2); i += 1024) {
            const float4 v = lp4[i];
            const int4   t = t4[i];
            cA += v.x + v.y + v.z + v.w;
            if (t.x) c1 += v.x;
            if (t.y) c1 += v.y;
            if (t.z) c1 += v.z;
            if (t.w) c1 += v.w;
        }
    } else {
        for (int i = tid; i < N; i += 1024) {
            const float v = logp[i];
            cA += v;
            if (target[i]) c1 += v;
        }
    }
    __shared__ float s0[1024];
    __shared__ float s1[1024];
    s0[tid] = cA; s1[tid] = c1;
    __syncthreads();
    for (int off = 512; off > 0; off >>= 1) {
        if (tid < off) {
            s0[tid] += s0[tid + off];
            s1[tid] += s1[tid + off];
        }
        __syncthreads();
    }
    if (tid == 0) {
        const float lp0 = (s0[0] - s1[0]) / stats[4];
        const float lp1 = s1[0] / stats[5];
        const float ld0 = stats[2] / stats[4];
        const float ld1 = stats[3] / stats[5];
        out[out_off]     = lp0;            // log_p_total[0]
        out[out_off + 1] = lp1;            // log_p_total[1]
        out[0] = 0.5f * ((lp0 + ld0) + (lp1 + ld1));  // prior_logprob
    }
}

extern "C" void kernel_launch(void* const* d_in, const int* in_sizes, int n_in,
                              void* d_out, int out_size, void* d_ws, size_t ws_size,
                              hipStream_t stream)
{
    const float* z      = (const float*)d_in[0];
    const float* mean   = (const float*)d_in[1];
    const float* log_sd = (const float*)d_in[2];
    const float* logdet = (const float*)d_in[3];
    const int*   target = (const int*)d_in[4];
    float* out = (float*)d_out;
    float* ws  = (float*)d_ws;

    const int N = in_sizes[3];            // 8192
    const int D = in_sizes[0] / N;        // 3072
    const int D4 = D >> 2;                // 768
    const int gx = (D4 + BLOCK - 1) / BLOCK;   // 3

    // regions
    float* tgtf = ws + 16 + 6 * D;
    size_t part0 = (size_t)(16 + 6 * D + N);
    part0 = (part0 + 255) & ~(size_t)255;

    // pick gyR (power of 2) so partials fit in ws
    int gyR = 128;
    while (gyR > 1 &&
           (part0 + (size_t)2 * gyR * gx * 2048) * sizeof(float) > ws_size)
        gyR >>= 1;
    int rowsPerBlk = (N + gyR - 1) / gyR;

    float* partials = ws + part0;

    // prep: tgtf + counts + logdet sums
    k_prep<<<1, 1024, 0, stream>>>(target, logdet, tgtf, ws, N);

    // pass 1: streaming per-class column partial sums
    dim3 g1(gx, gyR, 2);
    k_colsum<<<g1, BLOCK, 0, stream>>>(mean, log_sd, tgtf, partials,
                                       N, D4, rowsPerBlk, gyR);

    // reduce partials + finalize class params + build logp tables
    const int tot = 2 * D;
    k_reduce_finalize<<<(tot + BLOCK - 1) / BLOCK, BLOCK, 0, stream>>>(
        partials, ws, ws, out, D, gx, gyR);

    // pass 2: per-sample logp (one wave per row)
    float* logp_out = out + 1 + 4 * D;
    k_logp<<<(N + 3) / 4, BLOCK, 0, stream>>>(z, target, ws, logp_out, N, D);

    // epilogue: class logp means + prior
    k_finalize2<<<1, 1024, 0, stream>>>(logp_out, target, ws, out,
                                        N, 1 + 4 * D + N);
}